// Round 2
// baseline (647.369 us; speedup 1.0000x reference)
//
#include <hip/hip_runtime.h>
#include <hip/hip_bf16.h>

// Problem: B=4, C=64, D=32, H=64, W=64, S=32. Inputs/outputs fp32 (reference dtype).
#define Bn 4
#define Cn 64
#define Dn 32
#define Sn 32
#define Hn 64
#define Wn 64
#define HWn 4096
#define TW 8            // w-sites per block
#define NT 256          // 32 lanes (d) x 8 sites

typedef unsigned short us8v __attribute__((ext_vector_type(8)));

__device__ __forceinline__ unsigned short f2bf(float f) {
    union { __hip_bfloat16 h; unsigned short u; } cv;
    cv.h = __float2bfloat16(f);   // RNE
    return cv.u;
}
__device__ __forceinline__ float bf2f(unsigned short u) {
    return __uint_as_float(((unsigned int)u) << 16);
}

__global__ __launch_bounds__(NT, 2) void attn_kernel(
    const float* __restrict__ x,
    const float* __restrict__ Wk, const float* __restrict__ bk,
    const float* __restrict__ Wq, const float* __restrict__ bq,
    const float* __restrict__ Wv, const float* __restrict__ bv,
    const float* __restrict__ Wo, const float* __restrict__ bo,
    float* __restrict__ out)
{
    __shared__ unsigned short xt[Cn][Dn][TW];   // 32 KB bf16 x-tile; reused for out
    __shared__ unsigned short kb[TW][Sn][Dn];   // 16 KB bf16 K
    __shared__ unsigned short vb[TW][Sn][Dn];   // 16 KB bf16 V   (total 64 KB)

    const int t = threadIdx.x;
    // Pair-swizzle: blocks i and i+8 land on the same XCD (round-robin %8) and
    // cover the two 32B halves of each 64B x/out line -> L2 absorbs split lines.
    const int i      = blockIdx.x;               // 0..2047
    const int member = (i >> 3) & 1;
    const int p      = (i & 7) | ((i >> 4) << 3); // pair id 0..1023
    const int wpair  = p & 3;
    const int bh     = p >> 2;
    const int h      = bh & (Hn - 1);
    const int b      = bh >> 6;
    const int w0     = wpair * 16 + member * TW;

    const size_t base = (size_t)b * (Cn * Dn * HWn) + h * Wn + w0;

    // ---- Stage x tile (fp32 global -> bf16 LDS), 32B per (c,d) row ----
    for (int idx = t; idx < Cn * Dn; idx += NT) {
        const int c = idx >> 5, d = idx & 31;
        const float* px = x + base + (size_t)(c * Dn + d) * HWn;
        const float4 f0 = *(const float4*)px;
        const float4 f1 = *(const float4*)(px + 4);
        us8v v;
        v[0] = f2bf(f0.x); v[1] = f2bf(f0.y); v[2] = f2bf(f0.z); v[3] = f2bf(f0.w);
        v[4] = f2bf(f1.x); v[5] = f2bf(f1.y); v[6] = f2bf(f1.z); v[7] = f2bf(f1.w);
        *(us8v*)&xt[c][d][0] = v;
    }
    __syncthreads();

    const int d    = t & 31;   // column (D axis) owned by this lane
    const int site = t >> 5;   // which w-site

    // ---- QKV projection: all 96 accumulators live; weights are wave-uniform
    //      (s_load into SGPRs, FMA with SGPR operand) ----
    float ak[Sn], aq[Sn], av[Sn];
#pragma unroll
    for (int s = 0; s < Sn; ++s) {
        ak[s] = bk[s]; aq[s] = bq[s]; av[s] = bv[s];
    }
    for (int cb = 0; cb < Cn; cb += 8) {
        float xv[8];
#pragma unroll
        for (int cc = 0; cc < 8; ++cc) xv[cc] = bf2f(xt[cb + cc][d][site]);
#pragma unroll
        for (int s = 0; s < Sn; ++s) {
#pragma unroll
            for (int cc = 0; cc < 8; ++cc) {
                const int wi = s * Cn + cb + cc;
                ak[s] += xv[cc] * Wk[wi];
                aq[s] += xv[cc] * Wq[wi];
                av[s] += xv[cc] * Wv[wi];
            }
        }
    }
#pragma unroll
    for (int s = 0; s < Sn; ++s) {
        kb[site][s][d] = f2bf(ak[s]);
        vb[site][s][d] = f2bf(av[s]);
    }
    __syncthreads();

    // ---- scores[i][j=d] = (1/sqrt(S)) * sum_s k[s][i]*q[s][d]; K rows are
    //      lane-uniform b128 broadcasts ----
    float a_[Dn];
#pragma unroll
    for (int ii = 0; ii < Dn; ++ii) a_[ii] = 0.f;
#pragma unroll 4
    for (int s = 0; s < Sn; ++s) {
        const float qs = aq[s];
        const us8v* kr = (const us8v*)&kb[site][s][0];
#pragma unroll
        for (int i0 = 0; i0 < 4; ++i0) {
            const us8v kv = kr[i0];
#pragma unroll
            for (int m = 0; m < 8; ++m)
                a_[i0 * 8 + m] += bf2f(kv[m]) * qs;
        }
    }
    const float scale = 0.17677669529663687f;   // 1/sqrt(32)
#pragma unroll
    for (int ii = 0; ii < Dn; ++ii) a_[ii] *= scale;

    // ---- softmax over i (axis -2), per-lane in registers ----
    float mx = a_[0];
#pragma unroll
    for (int ii = 1; ii < Dn; ++ii) mx = fmaxf(mx, a_[ii]);
    float sum = 0.f;
#pragma unroll
    for (int ii = 0; ii < Dn; ++ii) { a_[ii] = __expf(a_[ii] - mx); sum += a_[ii]; }
    const float inv = 1.0f / sum;
#pragma unroll
    for (int ii = 0; ii < Dn; ++ii) a_[ii] *= inv;

    // ---- o[s][d] = sum_i v[s][i] * a[i][d] ----
    float ocol[Sn];
#pragma unroll 2
    for (int s = 0; s < Sn; ++s) {
        const us8v* vr = (const us8v*)&vb[site][s][0];
        float c0 = 0.f, c1 = 0.f, c2 = 0.f, c3 = 0.f;
#pragma unroll
        for (int i0 = 0; i0 < 4; ++i0) {
            const us8v vv = vr[i0];
            c0 += bf2f(vv[0]) * a_[i0 * 8 + 0];
            c1 += bf2f(vv[1]) * a_[i0 * 8 + 1];
            c2 += bf2f(vv[2]) * a_[i0 * 8 + 2];
            c3 += bf2f(vv[3]) * a_[i0 * 8 + 3];
            c0 += bf2f(vv[4]) * a_[i0 * 8 + 4];
            c1 += bf2f(vv[5]) * a_[i0 * 8 + 5];
            c2 += bf2f(vv[6]) * a_[i0 * 8 + 6];
            c3 += bf2f(vv[7]) * a_[i0 * 8 + 7];
        }
        ocol[s] = (c0 + c1) + (c2 + c3);
    }

    // ---- out[c][d] = x[c][d] + bo[c] + sum_s Wo[c][s]*o[s][d]; write own slot ----
#pragma unroll 4
    for (int c = 0; c < Cn; ++c) {
        float acc = bo[c];
#pragma unroll
        for (int s = 0; s < Sn; ++s) acc += Wo[c * Sn + s] * ocol[s];
        const float res = bf2f(xt[c][d][site]) + acc;   // residual (x in bf16)
        xt[c][d][site] = f2bf(res);                     // lane-owned slot, no race
    }
    __syncthreads();

    // ---- Coalesced fp32 store of the residual-added tile ----
    for (int idx = t; idx < Cn * Dn; idx += NT) {
        const int c = idx >> 5, dd = idx & 31;
        const us8v v = *(const us8v*)&xt[c][dd][0];
        float* po = out + base + (size_t)(c * Dn + dd) * HWn;
        float4 f0, f1;
        f0.x = bf2f(v[0]); f0.y = bf2f(v[1]); f0.z = bf2f(v[2]); f0.w = bf2f(v[3]);
        f1.x = bf2f(v[4]); f1.y = bf2f(v[5]); f1.z = bf2f(v[6]); f1.w = bf2f(v[7]);
        *(float4*)po = f0;
        *(float4*)(po + 4) = f1;
    }
}

extern "C" void kernel_launch(void* const* d_in, const int* in_sizes, int n_in,
                              void* d_out, int out_size, void* d_ws, size_t ws_size,
                              hipStream_t stream) {
    (void)in_sizes; (void)n_in; (void)d_ws; (void)ws_size; (void)out_size;
    const float* x  = (const float*)d_in[0];
    const float* Wk = (const float*)d_in[1];
    const float* bk = (const float*)d_in[2];
    const float* Wq = (const float*)d_in[3];
    const float* bq = (const float*)d_in[4];
    const float* Wv = (const float*)d_in[5];
    const float* bv = (const float*)d_in[6];
    const float* Wo = (const float*)d_in[7];
    const float* bo = (const float*)d_in[8];
    float* out = (float*)d_out;

    const int nblocks = Bn * Hn * (Wn / TW);   // 2048
    attn_kernel<<<dim3(nblocks), dim3(NT), 0, stream>>>(
        x, Wk, bk, Wq, bq, Wv, bv, Wo, bo, out);
}

// Round 3
// 370.652 us; speedup vs baseline: 1.7466x; 1.7466x over previous
//
#include <hip/hip_runtime.h>
#include <hip/hip_bf16.h>

// B=4, C=64, D=32, H=64, W=64, S=32. fp32 I/O, bf16 MFMA compute.
#define Bn 4
#define Cn 64
#define Dn 32
#define Sn 32
#define Hn 64
#define Wn 64
#define HWn 4096
#define NT 256

// Per-wave LDS slice (shorts). Aliased in time:
//   phase1: xT[64 rows][66]  (rows n_local = (site&1)*32 + d, cols c)
//   phase2: kT[2][32][34] (+0) and vb[2][32][36] (+2176)
//   phase3: outT[64][66]
#define SLICE   4608      // shorts = 9216 B per wave
#define XPITCH  66
#define KT_SITE 1088      // 32*34
#define VB_OFF  2176
#define VB_SITE 1152      // 32*36
#define BIAS_U32 9216     // uint index where bias floats start (160 floats)

typedef float f16v __attribute__((ext_vector_type(16)));
typedef short s8v  __attribute__((ext_vector_type(8)));
#define MFMA(a,b,c) __builtin_amdgcn_mfma_f32_32x32x16_bf16((a),(b),(c),0,0,0)

union frag_u { s8v v; unsigned short u[8]; unsigned int d[4]; };

__device__ __forceinline__ unsigned short f2bf(float f){
    union { __hip_bfloat16 h; unsigned short u; } cv; cv.h = __float2bfloat16(f); return cv.u;
}
__device__ __forceinline__ float bf2f(unsigned short u){
    return __uint_as_float(((unsigned int)u)<<16);
}
__device__ __forceinline__ f16v zero16(){
    f16v z;
#pragma unroll
    for(int i=0;i<16;++i) z[i]=0.f;
    return z;
}
// A-operand fragment from a row-major fp32 weight matrix: A[m=row][k=c0..c0+7]
__device__ __forceinline__ s8v wfrag(const float* __restrict__ W, int stride, int row, int c0){
    const float4 a = *(const float4*)(W + row*stride + c0);
    const float4 b = *(const float4*)(W + row*stride + c0 + 4);
    frag_u f;
    f.u[0]=f2bf(a.x); f.u[1]=f2bf(a.y); f.u[2]=f2bf(a.z); f.u[3]=f2bf(a.w);
    f.u[4]=f2bf(b.x); f.u[5]=f2bf(b.y); f.u[6]=f2bf(b.z); f.u[7]=f2bf(b.w);
    return f.v;
}
// Assemble B-operand fragment (chunk ch of a K=32 contraction) from C/D-layout
// fp32 regs a[16] + their shfl_xor(32) partners sw[16].
// C/D row of reg r = (r&3)+8*(r>>2)+4*hi; B needs k = ch*16 + hi*8 + e.
__device__ __forceinline__ s8v bfrag(const float a[16], const float sw[16], int ch, int hi){
    frag_u f;
    const int b = ch*8;
#pragma unroll
    for(int j=0;j<4;++j){
        const float lo = hi ? sw[b+4+j] : a[b+j];    // e = j
        const float hh = hi ? a[b+4+j]  : sw[b+j];   // e = 4+j
        f.u[j]   = f2bf(lo);
        f.u[4+j] = f2bf(hh);
    }
    return f.v;
}

__global__ __launch_bounds__(NT) void attn_kernel(
    const float* __restrict__ x,
    const float* __restrict__ Wk, const float* __restrict__ bk,
    const float* __restrict__ Wq, const float* __restrict__ bq,
    const float* __restrict__ Wv, const float* __restrict__ bv,
    const float* __restrict__ Wo, const float* __restrict__ bo,
    float* __restrict__ out)
{
    __shared__ unsigned int lds32[BIAS_U32 + 160];   // 4 slices + biases = 37.5 KB
    unsigned short* lds16 = (unsigned short*)lds32;
    float* biasf = (float*)(lds32 + BIAS_U32);

    const int t = threadIdx.x;
    // XCD pair swizzle (kept from R2: blocks i,i+8 share 64B x/out lines via L2)
    const int ib = blockIdx.x;
    const int member = (ib>>3)&1;
    const int pp = (ib&7) | ((ib>>4)<<3);
    const int wpair = pp & 3;
    const int bh = pp >> 2;
    const int h = bh & (Hn-1);
    const int b = bh >> 6;
    const int w0 = wpair*16 + member*8;
    const size_t base = (size_t)b*(Cn*Dn*HWn) + h*Wn + w0;

    // ---- Phase 0: stage x -> xT bf16 (transposed [n][c], per-wave slices) ----
    for (int u=t; u<1024; u+=NT){
        const int cp = u>>5, d = u&31;
        const float* p0 = x + base + (size_t)((2*cp)*Dn + d)*HWn;
        const float* p1 = p0 + (size_t)Dn*HWn;
        const float4 a0 = ((const float4*)p0)[0], a1 = ((const float4*)p0)[1];
        const float4 b0 = ((const float4*)p1)[0], b1 = ((const float4*)p1)[1];
        const float r0[8] = {a0.x,a0.y,a0.z,a0.w,a1.x,a1.y,a1.z,a1.w};
        const float r1[8] = {b0.x,b0.y,b0.z,b0.w,b1.x,b1.y,b1.z,b1.w};
#pragma unroll
        for(int site=0;site<8;++site){
            const unsigned int pk = (unsigned int)f2bf(r0[site])
                                  | ((unsigned int)f2bf(r1[site])<<16);
            const int off = (site>>1)*SLICE + (((site&1)<<5)+d)*XPITCH + 2*cp;
            lds32[off>>1] = pk;   // shorts (2cp,2cp+1) of row n=site*32+d
        }
    }
    if (t < 160){
        const float v = (t<32)? bk[t] : (t<64)? bq[t-32] : (t<96)? bv[t-64] : bo[t-96];
        biasf[t] = v;
    }
    __syncthreads();

    const int wv = t>>6, lane = t&63, ln = lane&31, hi = lane>>5;
    const int WSH = wv*SLICE;

    // ---- B-fragments of X for this wave's 2 sites (frees xT slice afterwards) ----
    frag_u xb[2][4];
#pragma unroll
    for(int st=0;st<2;++st){
        const int nl = (st<<5)+ln;
#pragma unroll
        for(int kc=0;kc<4;++kc){
            const unsigned int* q = lds32 + ((WSH + nl*XPITCH + kc*16 + hi*8)>>1);
            xb[st][kc].d[0]=q[0]; xb[st][kc].d[1]=q[1];
            xb[st][kc].d[2]=q[2]; xb[st][kc].d[3]=q[3];
        }
    }
    const float scale = 0.17677669529663687f;   // 1/sqrt(32)

    // ---- K = Wk @ X  -> kT[site][i][s] (bias+scale folded), aliases xT slice ----
    {
        f16v k0=zero16(), k1=zero16();
#pragma unroll
        for(int kc=0;kc<4;++kc){
            const s8v wa = wfrag(Wk, Cn, ln, kc*16+hi*8);
            k0 = MFMA(wa, xb[0][kc].v, k0);
            k1 = MFMA(wa, xb[1][kc].v, k1);
        }
#pragma unroll
        for(int r=0;r<16;++r){
            const int s = (r&3)+8*(r>>2)+4*hi;
            lds16[WSH + 0*KT_SITE + ln*34 + s] = f2bf((k0[r]+biasf[s])*scale);
            lds16[WSH + 1*KT_SITE + ln*34 + s] = f2bf((k1[r]+biasf[s])*scale);
        }
    }
    // ---- Q = Wq @ X  -> kept in registers as B-fragments ----
    frag_u qf[2][2];
    {
        f16v q0=zero16(), q1=zero16();
#pragma unroll
        for(int kc=0;kc<4;++kc){
            const s8v wa = wfrag(Wq, Cn, ln, kc*16+hi*8);
            q0 = MFMA(wa, xb[0][kc].v, q0);
            q1 = MFMA(wa, xb[1][kc].v, q1);
        }
        float qa[16], qb_[16], sw[16];
#pragma unroll
        for(int r=0;r<16;++r){
            const int s = (r&3)+8*(r>>2)+4*hi;
            qa[r]  = q0[r] + biasf[32+s];
            qb_[r] = q1[r] + biasf[32+s];
        }
#pragma unroll
        for(int r=0;r<16;++r) sw[r] = __shfl_xor(qa[r], 32);
        qf[0][0].v = bfrag(qa, sw, 0, hi);
        qf[0][1].v = bfrag(qa, sw, 1, hi);
#pragma unroll
        for(int r=0;r<16;++r) sw[r] = __shfl_xor(qb_[r], 32);
        qf[1][0].v = bfrag(qb_, sw, 0, hi);
        qf[1][1].v = bfrag(qb_, sw, 1, hi);
    }
    // ---- V = Wv @ X  -> vb[site][s][i] ----
    {
        f16v v0=zero16(), v1=zero16();
#pragma unroll
        for(int kc=0;kc<4;++kc){
            const s8v wa = wfrag(Wv, Cn, ln, kc*16+hi*8);
            v0 = MFMA(wa, xb[0][kc].v, v0);
            v1 = MFMA(wa, xb[1][kc].v, v1);
        }
#pragma unroll
        for(int r=0;r<16;++r){
            const int s = (r&3)+8*(r>>2)+4*hi;
            lds16[WSH + VB_OFF + 0*VB_SITE + s*36 + ln] = f2bf(v0[r]+biasf[64+s]);
            lds16[WSH + VB_OFF + 1*VB_SITE + s*36 + ln] = f2bf(v1[r]+biasf[64+s]);
        }
    }

    // ---- scores -> softmax(axis i) -> PV, per site; O kept as B-fragments ----
    frag_u of[2][2];
#pragma unroll
    for(int st=0; st<2; ++st){
        frag_u ka[2], va[2];
#pragma unroll
        for(int ch=0; ch<2; ++ch){
            const unsigned int* qk = lds32 + ((WSH + st*KT_SITE + ln*34 + ch*16 + hi*8)>>1);
            ka[ch].d[0]=qk[0]; ka[ch].d[1]=qk[1]; ka[ch].d[2]=qk[2]; ka[ch].d[3]=qk[3];
            const unsigned int* qv = lds32 + ((WSH + VB_OFF + st*VB_SITE + ln*36 + ch*16 + hi*8)>>1);
            va[ch].d[0]=qv[0]; va[ch].d[1]=qv[1]; va[ch].d[2]=qv[2]; va[ch].d[3]=qv[3];
        }
        f16v sc = zero16();                     // sc[i][j] = sum_s kT[i][s] q[s][j]
        sc = MFMA(ka[0].v, qf[st][0].v, sc);
        sc = MFMA(ka[1].v, qf[st][1].v, sc);

        float mx = sc[0];
#pragma unroll
        for(int r=1;r<16;++r) mx = fmaxf(mx, sc[r]);
        mx = fmaxf(mx, __shfl_xor(mx, 32));
        float pr[16]; float sm = 0.f;
#pragma unroll
        for(int r=0;r<16;++r){ pr[r] = __expf(sc[r]-mx); sm += pr[r]; }
        sm += __shfl_xor(sm, 32);
        const float inv = 1.f/sm;
#pragma unroll
        for(int r=0;r<16;++r) pr[r] *= inv;

        float swp[16];
#pragma unroll
        for(int r=0;r<16;++r) swp[r] = __shfl_xor(pr[r], 32);
        frag_u pf0, pf1;
        pf0.v = bfrag(pr, swp, 0, hi);
        pf1.v = bfrag(pr, swp, 1, hi);

        f16v ov = zero16();                     // o[s][j] = sum_i v[s][i] p[i][j]
        ov = MFMA(va[0].v, pf0.v, ov);
        ov = MFMA(va[1].v, pf1.v, ov);

        float oa_[16], swo[16];
#pragma unroll
        for(int r=0;r<16;++r) oa_[r] = ov[r];
#pragma unroll
        for(int r=0;r<16;++r) swo[r] = __shfl_xor(oa_[r], 32);
        of[st][0].v = bfrag(oa_, swo, 0, hi);
        of[st][1].v = bfrag(oa_, swo, 1, hi);
    }

    // ---- out-projection: D[c][n] = sum_s Wo[c][s] o[s][n] -> outT (aliases kT/vb) ----
    frag_u wo_[2][2];
#pragma unroll
    for(int mt=0; mt<2; ++mt)
#pragma unroll
        for(int ch=0; ch<2; ++ch)
            wo_[mt][ch].v = wfrag(Wo, Sn, mt*32+ln, ch*16+hi*8);
#pragma unroll
    for(int st=0; st<2; ++st){
#pragma unroll
        for(int mt=0; mt<2; ++mt){
            f16v oacc = zero16();
            oacc = MFMA(wo_[mt][0].v, of[st][0].v, oacc);
            oacc = MFMA(wo_[mt][1].v, of[st][1].v, oacc);
#pragma unroll
            for(int r=0;r<16;++r){
                const int c = mt*32 + (r&3)+8*(r>>2)+4*hi;
                lds16[WSH + ((st<<5)+ln)*XPITCH + c] = f2bf(oacc[r]);
            }
        }
    }
    __syncthreads();

    // ---- Epilogue: residual (coalesced x re-read) + bo + coalesced fp32 store ----
    for (int u=t; u<1024; u+=NT){
        const int cp=u>>5, d=u&31;
        const int c0=2*cp, c1=c0+1;
        const float* p0 = x + base + (size_t)(c0*Dn + d)*HWn;
        const float* p1 = p0 + (size_t)Dn*HWn;
        const float4 a0 = ((const float4*)p0)[0], a1 = ((const float4*)p0)[1];
        const float4 b0 = ((const float4*)p1)[0], b1 = ((const float4*)p1)[1];
        const float r0[8] = {a0.x,a0.y,a0.z,a0.w,a1.x,a1.y,a1.z,a1.w};
        const float r1[8] = {b0.x,b0.y,b0.z,b0.w,b1.x,b1.y,b1.z,b1.w};
        const float bo0 = biasf[96+c0], bo1 = biasf[96+c1];
        float o0[8], o1[8];
#pragma unroll
        for(int site=0;site<8;++site){
            const int off = (site>>1)*SLICE + (((site&1)<<5)+d)*XPITCH + c0;
            const unsigned int pk = lds32[off>>1];
            o0[site] = r0[site] + bo0 + bf2f((unsigned short)(pk & 0xffffu));
            o1[site] = r1[site] + bo1 + bf2f((unsigned short)(pk >> 16));
        }
        float* q0p = out + base + (size_t)(c0*Dn + d)*HWn;
        float* q1p = q0p + (size_t)Dn*HWn;
        ((float4*)q0p)[0] = make_float4(o0[0],o0[1],o0[2],o0[3]);
        ((float4*)q0p)[1] = make_float4(o0[4],o0[5],o0[6],o0[7]);
        ((float4*)q1p)[0] = make_float4(o1[0],o1[1],o1[2],o1[3]);
        ((float4*)q1p)[1] = make_float4(o1[4],o1[5],o1[6],o1[7]);
    }
}

extern "C" void kernel_launch(void* const* d_in, const int* in_sizes, int n_in,
                              void* d_out, int out_size, void* d_ws, size_t ws_size,
                              hipStream_t stream) {
    (void)in_sizes; (void)n_in; (void)d_ws; (void)ws_size; (void)out_size;
    const float* x  = (const float*)d_in[0];
    const float* Wk = (const float*)d_in[1];
    const float* bk = (const float*)d_in[2];
    const float* Wq = (const float*)d_in[3];
    const float* bq = (const float*)d_in[4];
    const float* Wv = (const float*)d_in[5];
    const float* bv = (const float*)d_in[6];
    const float* Wo = (const float*)d_in[7];
    const float* bo = (const float*)d_in[8];
    float* out = (float*)d_out;

    const int nblocks = Bn * Hn * (Wn / 8);   // 2048
    attn_kernel<<<dim3(nblocks), dim3(NT), 0, stream>>>(
        x, Wk, bk, Wq, bq, Wv, bv, Wo, bo, out);
}